// Round 1
// baseline (2406.438 us; speedup 1.0000x reference)
//
#include <hip/hip_runtime.h>

constexpr int BATCH = 4;
constexpr int H = 96, W = 96, HW = H * W;
constexpr int NBR = 3;

static __device__ __forceinline__ float leakyf(float x) {
    return x >= 0.f ? x : 0.1f * x;
}

// ---- fold w1 (in = concat([ref, ref])) to a 64-ch weight -------------------
__global__ void k_fold_w1(const float* __restrict__ w1, float* __restrict__ wf) {
    int i = blockIdx.x * 256 + threadIdx.x;
    if (i >= 64 * 64 * 9) return;
    int k = i % 9, c = (i / 9) % 64, o = i / (64 * 9);
    wf[i] = w1[(o * 128 + c) * 9 + k] + w1[(o * 128 + 64 + c) * 9 + k];
}

// ---- transpose wnn (64,192,3,3) -> [ic][k][oc] for coalesced reads ---------
__global__ void k_twnn(const float* __restrict__ wnn, float* __restrict__ wt) {
    int i = blockIdx.x * 256 + threadIdx.x;
    if (i >= 64 * 192 * 9) return;
    int k = i % 9, ic = (i / 9) % 192, o = i / (192 * 9);
    wt[(ic * 9 + k) * 64 + o] = wnn[i];
}

// ---- generic direct conv, LDS-tiled: tile 32x8 pixels, 8-ch chunks ---------
// input tensors are physically 64-channel; IC=128 uses in2 for channels 64..127
template <int KH, int KW, int PH, int PW, int OC, int IC, bool LK>
__global__ __launch_bounds__(256) void k_conv(
    const float* __restrict__ in1, const float* __restrict__ in2,
    const float* __restrict__ wt, const float* __restrict__ bs,
    float* __restrict__ out) {
    constexpr int TJ = 32, TI = 8, CH = 8;
    constexpr int LR = TI + KH - 1, LC = TJ + KW - 1;
    __shared__ float sm[CH][LR][LC];
    const int tj0 = blockIdx.x * TJ;
    const int ti0 = blockIdx.y * TI;
    const int oc = blockIdx.z % OC;
    const int b = blockIdx.z / OC;
    const int tid = threadIdx.x;
    const int lj = tid % TJ, li = tid / TJ;
    float acc = 0.f;
    for (int cc = 0; cc < IC; cc += CH) {
        const float* src = (cc < 64) ? in1 : in2;
        const int cb = (cc < 64) ? cc : cc - 64;
        constexpr int NE = CH * LR * LC;
        __syncthreads();
        for (int e = tid; e < NE; e += 256) {
            int c = e / (LR * LC);
            int r = (e / LC) % LR;
            int col = e % LC;
            int gi = ti0 + r - PH, gj = tj0 + col - PW;
            float v = 0.f;
            if (gi >= 0 && gi < H && gj >= 0 && gj < W)
                v = src[(b * 64 + cb + c) * HW + gi * W + gj];
            sm[c][r][col] = v;
        }
        __syncthreads();
#pragma unroll
        for (int c = 0; c < CH; ++c)
#pragma unroll
            for (int u = 0; u < KH; ++u)
#pragma unroll
                for (int v = 0; v < KW; ++v)
                    acc += wt[((oc * IC + cc + c) * KH + u) * KW + v] *
                           sm[c][li + u][lj + v];
    }
    acc += bs[oc];
    if (LK) acc = leakyf(acc);
    out[(b * OC + oc) * HW + (ti0 + li) * W + (tj0 + lj)] = acc;
}

// ---- channel-wise L2 normalize --------------------------------------------
__global__ void k_norm(const float* __restrict__ in, float* __restrict__ out) {
    int p = blockIdx.x * 256 + threadIdx.x;
    if (p >= BATCH * HW) return;
    int b = p / HW, ij = p % HW;
    const float* src = in + b * 64 * HW + ij;
    float ss = 0.f;
#pragma unroll
    for (int c = 0; c < 64; ++c) {
        float v = src[c * HW];
        ss += v * v;
    }
    float n = sqrtf(ss);
    float inv = 1.f / fmaxf(n, 1e-12f);
    float* dst = out + b * 64 * HW + ij;
#pragma unroll
    for (int c = 0; c < 64; ++c) dst[c * HW] = src[c * HW] * inv;
}

// ---- per-displacement dot map S[b][d][y][x], y,x in [0,98) (f1p coords) ----
__global__ void k_corr(const float* __restrict__ nr, float* __restrict__ S) {
    int idx = blockIdx.x * 256 + threadIdx.x;
    if (idx >= BATCH * 49 * 98 * 98) return;
    int x = idx % 98;
    int y = (idx / 98) % 98;
    int d = (idx / (98 * 98)) % 49;
    int b = idx / (98 * 98 * 49);
    int f1i = y - 1, f1j = x - 1;
    int f2i = y + d / 7 - 4, f2j = x + d % 7 - 4;
    float r = 0.f;
    if (f1i >= 0 && f1i < H && f1j >= 0 && f1j < W && f2i >= 0 && f2i < H &&
        f2j >= 0 && f2j < W) {
        const float* p1 = nr + b * 64 * HW + f1i * W + f1j;
        const float* p2 = nr + b * 64 * HW + f2i * W + f2j;
#pragma unroll 16
        for (int c = 0; c < 64; ++c) r += p1[c * HW] * p2[c * HW];
    }
    S[idx] = r;
}

// ---- 3x3 window-sum per displacement + top-3 (stable: strict >) ------------
__global__ void k_topk(const float* __restrict__ S, int* __restrict__ idx3) {
    int p = blockIdx.x * 256 + threadIdx.x;
    if (p >= BATCH * HW) return;
    int b = p / HW, i = (p % HW) / W, j = p % W;
    float v0 = -1e30f, v1 = -1e30f, v2 = -1e30f;
    int d0 = 0, d1 = 0, d2 = 0;
    for (int d = 0; d < 49; ++d) {
        const float* s = S + ((b * 49 + d) * 98 + i) * 98 + j;
        float v = 0.f;
#pragma unroll
        for (int u = 0; u < 3; ++u)
#pragma unroll
            for (int vv = 0; vv < 3; ++vv) v += s[u * 98 + vv];
        if (v > v0) {
            v2 = v1; d2 = d1; v1 = v0; d1 = d0; v0 = v; d0 = d;
        } else if (v > v1) {
            v2 = v1; d2 = d1; v1 = v; d1 = d;
        } else if (v > v2) {
            v2 = v; d2 = d;
        }
    }
    idx3[p * 3 + 0] = d0;
    idx3[p * 3 + 1] = d1;
    idx3[p * 3 + 2] = d2;
}

// ---- gather patches + 192->64 3x3 conv on 3x3 patch + mask reduce ----------
// block: 512 threads = 8 pixels x 64 out-channels
__global__ __launch_bounds__(512) void k_agg(
    const float* __restrict__ ref, const int* __restrict__ idx3,
    const float* __restrict__ wt, const float* __restrict__ bnn,
    const float* __restrict__ mask, float* __restrict__ agg) {
    constexpr int PX = 8;
    __shared__ float patch[PX][NBR][64][9];  // 55296 B
    __shared__ int sd[PX][NBR];
    const int p0 = blockIdx.x * PX;
    const int tid = threadIdx.x;
    const int b = p0 / HW;                    // uniform (HW % PX == 0)
    const int i0 = (p0 % HW) / W;
    const int j0 = p0 % W;                    // 8 consecutive j, same row
    if (tid < PX * NBR) sd[tid / NBR][tid % NBR] = idx3[(p0 + tid / NBR) * 3 + tid % NBR];
    __syncthreads();
    for (int e = tid; e < PX * NBR * 64 * 9; e += 512) {
        int k = e % 9;
        int c = (e / 9) % 64;
        int n = (e / (9 * 64)) % NBR;
        int px = e / (9 * 64 * NBR);
        int d = sd[px][n];
        int ph = d / 7, pw = d % 7;
        int r = k / 3, s = k % 3;
        int gi = i0 + ph + r - 4;
        int gj = j0 + px + pw + s - 4;
        float v = 0.f;
        if (gi >= 0 && gi < H && gj >= 0 && gj < W)
            v = ref[(b * 64 + c) * HW + gi * W + gj];
        patch[px][n][c][k] = v;
    }
    __syncthreads();
    const int px = tid >> 6;
    const int oc = tid & 63;
    float acc[3][3] = {};
    for (int n = 0; n < NBR; ++n)
        for (int c = 0; c < 64; ++c) {
            float pv[9];
#pragma unroll
            for (int k = 0; k < 9; ++k) pv[k] = patch[px][n][c][k];
            const float* wp = wt + (n * 64 + c) * 9 * 64 + oc;
            float wv[9];
#pragma unroll
            for (int k = 0; k < 9; ++k) wv[k] = wp[k * 64];
#pragma unroll
            for (int y = 0; y < 3; ++y)
#pragma unroll
                for (int x = 0; x < 3; ++x)
#pragma unroll
                    for (int u = 0; u < 3; ++u)
#pragma unroll
                        for (int v = 0; v < 3; ++v) {
                            int pi = y + u - 1, pj = x + v - 1;
                            if (pi >= 0 && pi < 3 && pj >= 0 && pj < 3)
                                acc[y][x] += wv[u * 3 + v] * pv[pi * 3 + pj];
                        }
        }
    float bn = bnn[oc];
    int g = oc >> 3;
    int ij = i0 * W + (j0 + px);
    float s = 0.f;
#pragma unroll
    for (int y = 0; y < 3; ++y)
#pragma unroll
        for (int x = 0; x < 3; ++x) {
            float gv = leakyf(acc[y][x] + bn);
            float mv = mask[(b * 72 + g * 9 + y * 3 + x) * HW + ij];
            s += gv * mv;
        }
    agg[(b * 64 + oc) * HW + ij] = leakyf(s);
}

extern "C" void kernel_launch(void* const* d_in, const int* in_sizes, int n_in,
                              void* d_out, int out_size, void* d_ws,
                              size_t ws_size, hipStream_t stream) {
    const float* ref = (const float*)d_in[0];
    const float* w1 = (const float*)d_in[1];
    const float* b1 = (const float*)d_in[2];
    const float* w2 = (const float*)d_in[3];
    const float* b2 = (const float*)d_in[4];
    const float* w3 = (const float*)d_in[5];
    const float* b3 = (const float*)d_in[6];
    const float* w4 = (const float*)d_in[7];
    const float* b4 = (const float*)d_in[8];
    const float* wm = (const float*)d_in[9];
    const float* bm = (const float*)d_in[10];
    const float* wnn = (const float*)d_in[11];
    const float* bnn = (const float*)d_in[12];
    const float* wf = (const float*)d_in[13];
    const float* bf = (const float*)d_in[14];

    char* ws = (char*)d_ws;
    constexpr size_t SZ_FEA = (size_t)BATCH * 64 * HW * 4;    // 9.44 MB
    constexpr size_t SZ_MASK = (size_t)BATCH * 72 * HW * 4;   // 10.6 MB
    constexpr size_t SZ_S = (size_t)BATCH * 49 * 98 * 98 * 4; // 7.53 MB
    constexpr size_t SZ_IDX = (size_t)BATCH * HW * 3 * 4;
    constexpr size_t SZ_WF1 = 64 * 64 * 9 * 4;
    float* A = (float*)(ws);
    float* Bt = (float*)(ws + SZ_FEA);
    float* MASK = (float*)(ws + 2 * SZ_FEA);
    float* S = (float*)(ws + 2 * SZ_FEA + SZ_MASK);
    int* IDX = (int*)(ws + 2 * SZ_FEA + SZ_MASK + SZ_S);
    float* WF1 = (float*)(ws + 2 * SZ_FEA + SZ_MASK + SZ_S + SZ_IDX);
    float* WT = (float*)(ws + 2 * SZ_FEA + SZ_MASK + SZ_S + SZ_IDX + SZ_WF1);

    // weight prep
    k_fold_w1<<<144, 256, 0, stream>>>(w1, WF1);
    k_twnn<<<(64 * 192 * 9 + 255) / 256, 256, 0, stream>>>(wnn, WT);

    dim3 cgrid(3, 12, BATCH * 64);
    dim3 mgrid(3, 12, BATCH * 72);

    // mask branch
    k_conv<3, 3, 1, 1, 64, 64, true><<<cgrid, 256, 0, stream>>>(ref, nullptr, WF1, b1, A);
    k_conv<3, 3, 1, 1, 64, 64, true><<<cgrid, 256, 0, stream>>>(A, nullptr, w2, b2, Bt);
    k_conv<7, 1, 3, 0, 64, 64, true><<<cgrid, 256, 0, stream>>>(Bt, nullptr, w3, b3, A);
    k_conv<1, 7, 0, 3, 64, 64, true><<<cgrid, 256, 0, stream>>>(A, nullptr, w4, b4, Bt);
    k_conv<3, 3, 1, 1, 72, 64, false><<<mgrid, 256, 0, stream>>>(Bt, nullptr, wm, bm, MASK);

    // correlation branch
    k_norm<<<(BATCH * HW + 255) / 256, 256, 0, stream>>>(ref, A);
    k_corr<<<(BATCH * 49 * 98 * 98 + 255) / 256, 256, 0, stream>>>(A, S);
    k_topk<<<BATCH * HW / 256, 256, 0, stream>>>(S, IDX);

    // gather + neighbor conv + mask-weighted aggregate  -> A (agg)
    k_agg<<<BATCH * HW / 8, 512, 0, stream>>>(ref, IDX, WT, bnn, MASK, A);

    // final fusion conv: concat([ref, agg]) -> out
    k_conv<3, 3, 1, 1, 64, 128, true><<<cgrid, 256, 0, stream>>>(ref, A, wf, bf, (float*)d_out);
}

// Round 2
// 1983.941 us; speedup vs baseline: 1.2130x; 1.2130x over previous
//
#include <hip/hip_runtime.h>
#include <hip/hip_bf16.h>

constexpr int BATCH = 4;
constexpr int H = 96, W = 96, HW = H * W;
constexpr int NBR = 3;

using bf16x8 = __attribute__((ext_vector_type(8))) short;  // 8 bf16 in 4 VGPRs
using f32x4 = __attribute__((ext_vector_type(4))) float;

static __device__ __forceinline__ float leakyf(float x) {
    return x >= 0.f ? x : 0.1f * x;
}

static __device__ __forceinline__ short f2bf(float x) {
    __hip_bfloat16 h = __float2bfloat16(x);
    return *reinterpret_cast<short*>(&h);
}

// ---- fold w1 (in = concat([ref, ref])) to a 64-ch weight -------------------
__global__ void k_fold_w1(const float* __restrict__ w1, float* __restrict__ wf) {
    int i = blockIdx.x * 256 + threadIdx.x;
    if (i >= 64 * 64 * 9) return;
    int k = i % 9, c = (i / 9) % 64, o = i / (64 * 9);
    wf[i] = w1[(o * 128 + c) * 9 + k] + w1[(o * 128 + 64 + c) * 9 + k];
}

// ---- build W2 in MFMA-B fragment layout ------------------------------------
// GEMM: out[p, n=yx*64+oc] = sum_k patch[p,k] * W2[k,n],
//   k=(nbr*64+c)*9+(r*3+s); W2 = wnn[oc, nbr*64+c, r-y+1, s-x+1] (0 if OOB)
// Bswz[kk(54)][nn(36)][lane(64)][e(8)] bf16, k = kk*32+(lane>>4)*8+e,
//   n = nn*16+(lane&15)
__global__ void k_bswz(const float* __restrict__ wnn, short* __restrict__ Bswz) {
    int i = blockIdx.x * 256 + threadIdx.x;
    if (i >= 54 * 36 * 64 * 8) return;
    int e = i & 7;
    int l = (i >> 3) & 63;
    int nn = (i >> 9) % 36;
    int kk = i / (36 * 64 * 8);
    int k = kk * 32 + (l >> 4) * 8 + e;
    int n = nn * 16 + (l & 15);
    int yx = n >> 6, oc = n & 63;
    int y = yx / 3, x = yx % 3;
    int nb = k / 576, c = (k / 9) % 64, rs = k % 9;
    int r = rs / 3, s = rs % 3;
    int u = r - y + 1, v = s - x + 1;
    float wv = 0.f;
    if (u >= 0 && u < 3 && v >= 0 && v < 3)
        wv = wnn[((oc * 192 + nb * 64 + c) * 3 + u) * 3 + v];
    Bswz[i] = f2bf(wv);
}

// ---- generic direct conv, LDS-tiled: tile 32x8 pixels, 8-ch chunks ---------
template <int KH, int KW, int PH, int PW, int OC, int IC, bool LK>
__global__ __launch_bounds__(256) void k_conv(
    const float* __restrict__ in1, const float* __restrict__ in2,
    const float* __restrict__ wt, const float* __restrict__ bs,
    float* __restrict__ out) {
    constexpr int TJ = 32, TI = 8, CH = 8;
    constexpr int LR = TI + KH - 1, LC = TJ + KW - 1;
    __shared__ float sm[CH][LR][LC];
    const int tj0 = blockIdx.x * TJ;
    const int ti0 = blockIdx.y * TI;
    const int oc = blockIdx.z % OC;
    const int b = blockIdx.z / OC;
    const int tid = threadIdx.x;
    const int lj = tid % TJ, li = tid / TJ;
    float acc = 0.f;
    for (int cc = 0; cc < IC; cc += CH) {
        const float* src = (cc < 64) ? in1 : in2;
        const int cb = (cc < 64) ? cc : cc - 64;
        constexpr int NE = CH * LR * LC;
        __syncthreads();
        for (int e = tid; e < NE; e += 256) {
            int c = e / (LR * LC);
            int r = (e / LC) % LR;
            int col = e % LC;
            int gi = ti0 + r - PH, gj = tj0 + col - PW;
            float v = 0.f;
            if (gi >= 0 && gi < H && gj >= 0 && gj < W)
                v = src[(b * 64 + cb + c) * HW + gi * W + gj];
            sm[c][r][col] = v;
        }
        __syncthreads();
#pragma unroll
        for (int c = 0; c < CH; ++c)
#pragma unroll
            for (int u = 0; u < KH; ++u)
#pragma unroll
                for (int v = 0; v < KW; ++v)
                    acc += wt[((oc * IC + cc + c) * KH + u) * KW + v] *
                           sm[c][li + u][lj + v];
    }
    acc += bs[oc];
    if (LK) acc = leakyf(acc);
    out[(b * OC + oc) * HW + (ti0 + li) * W + (tj0 + lj)] = acc;
}

// ---- L2 normalize + transpose to channel-last [b][ij][64] ------------------
__global__ void k_norm_t(const float* __restrict__ in, float* __restrict__ outT) {
    int p = blockIdx.x * 256 + threadIdx.x;
    if (p >= BATCH * HW) return;
    int b = p / HW, ij = p % HW;
    const float* src = in + b * 64 * HW + ij;
    float v[64];
    float ss = 0.f;
#pragma unroll
    for (int c = 0; c < 64; ++c) {
        v[c] = src[c * HW];
        ss += v[c] * v[c];
    }
    float inv = 1.f / fmaxf(sqrtf(ss), 1e-12f);
    float* dst = outT + (size_t)p * 64;
#pragma unroll
    for (int c = 0; c < 64; ++c) dst[c] = v[c] * inv;
}

// ---- per-displacement dot map S[b][d][y][x] from channel-last features -----
__global__ void k_corr_t(const float* __restrict__ nrT, float* __restrict__ S) {
    int idx = blockIdx.x * 256 + threadIdx.x;
    if (idx >= BATCH * 49 * 98 * 98) return;
    int x = idx % 98;
    int y = (idx / 98) % 98;
    int d = (idx / (98 * 98)) % 49;
    int b = idx / (98 * 98 * 49);
    int f1i = y - 1, f1j = x - 1;
    int f2i = y + d / 7 - 4, f2j = x + d % 7 - 4;
    float r = 0.f;
    if (f1i >= 0 && f1i < H && f1j >= 0 && f1j < W && f2i >= 0 && f2i < H &&
        f2j >= 0 && f2j < W) {
        const float4* p1 =
            (const float4*)(nrT + ((size_t)b * HW + f1i * W + f1j) * 64);
        const float4* p2 =
            (const float4*)(nrT + ((size_t)b * HW + f2i * W + f2j) * 64);
#pragma unroll
        for (int c = 0; c < 16; ++c) {
            float4 a = p1[c], bb = p2[c];
            r = fmaf(a.x, bb.x, r);
            r = fmaf(a.y, bb.y, r);
            r = fmaf(a.z, bb.z, r);
            r = fmaf(a.w, bb.w, r);
        }
    }
    S[idx] = r;
}

// ---- 3x3 window-sum per displacement + top-3 (stable: strict >) ------------
__global__ void k_topk(const float* __restrict__ S, int* __restrict__ idx3) {
    int p = blockIdx.x * 256 + threadIdx.x;
    if (p >= BATCH * HW) return;
    int b = p / HW, i = (p % HW) / W, j = p % W;
    float v0 = -1e30f, v1 = -1e30f, v2 = -1e30f;
    int d0 = 0, d1 = 0, d2 = 0;
    for (int d = 0; d < 49; ++d) {
        const float* s = S + ((b * 49 + d) * 98 + i) * 98 + j;
        float v = 0.f;
#pragma unroll
        for (int u = 0; u < 3; ++u)
#pragma unroll
            for (int vv = 0; vv < 3; ++vv) v += s[u * 98 + vv];
        if (v > v0) {
            v2 = v1; d2 = d1; v1 = v0; d1 = d0; v0 = v; d0 = d;
        } else if (v > v1) {
            v2 = v1; d2 = d1; v1 = v; d1 = d;
        } else if (v > v2) {
            v2 = v; d2 = d;
        }
    }
    idx3[p * 3 + 0] = d0;
    idx3[p * 3 + 1] = d1;
    idx3[p * 3 + 2] = d2;
}

// ---- MFMA gather-conv + mask reduce ----------------------------------------
// 32 pixels/block (same image row), 8 waves. GEMM: [32 x 1728] x [1728 x 576].
// A staged in LDS in fragment layout (two 16-px tiles); B streamed from L2 in
// pre-swizzled fragment layout. Wave w (0..3) + A-tile half: fixed oc slice
// [w*16, w*16+16), 9 acc tiles (one per output position yx).
__global__ __launch_bounds__(512) void k_agg_mfma(
    const float* __restrict__ ref, const int* __restrict__ idx3,
    const short* __restrict__ Bswz, const float* __restrict__ bnn,
    const float* __restrict__ mask, float* __restrict__ agg) {
    constexpr int PX = 32;
    __shared__ short A_lds[2][54][64][8];  // 110,592 B
    __shared__ int sd[PX][NBR];
    const int p0 = blockIdx.x * PX;
    const int b = p0 / HW;
    const int i0 = (p0 % HW) / W;
    const int j0 = p0 % W;
    const int tid = threadIdx.x;
    if (tid < PX * NBR)
        sd[tid / NBR][tid % NBR] = idx3[(p0 + tid / NBR) * NBR + tid % NBR];
    __syncthreads();
    // gather patches -> bf16 -> A fragment layout
    for (int e = tid; e < PX * NBR * 64 * 9; e += 512) {
        int k9 = e % 9;
        int c = (e / 9) % 64;
        int n = (e / (9 * 64)) % NBR;
        int px = e / (9 * 64 * NBR);
        int d = sd[px][n];
        int r = k9 / 3, s = k9 % 3;
        int gi = i0 + d / 7 + r - 4;
        int gj = j0 + px + d % 7 + s - 4;
        float v = 0.f;
        if (gi >= 0 && gi < H && gj >= 0 && gj < W)
            v = ref[(b * 64 + c) * HW + gi * W + gj];
        int kidx = (n * 64 + c) * 9 + k9;
        A_lds[px >> 4][kidx >> 5][((kidx & 31) >> 3) * 16 + (px & 15)][kidx & 7] =
            f2bf(v);
    }
    __syncthreads();
    const int wave = tid >> 6;
    const int lane = tid & 63;
    const int w = wave & 3;     // oc slice
    const int half = wave >> 2; // A tile (pixel group)
    f32x4 acc[9] = {};
    const short* Ap = &A_lds[half][0][lane][0];
    const short* Bp = Bswz + ((size_t)w * 64 + lane) * 8;
    for (int kk = 0; kk < 54; ++kk) {
        bf16x8 a = *(const bf16x8*)(Ap + kk * 64 * 8);
        const short* bp = Bp + (size_t)kk * 36 * 64 * 8;
#pragma unroll
        for (int yx = 0; yx < 9; ++yx) {
            bf16x8 bv = *(const bf16x8*)(bp + yx * 4 * 64 * 8);
            acc[yx] = __builtin_amdgcn_mfma_f32_16x16x32_bf16(a, bv, acc[yx], 0, 0, 0);
        }
    }
    // epilogue: bias -> leaky -> mask-weighted sum over 9 positions -> leaky
    const int oc = w * 16 + (lane & 15);
    const float bn = bnn[oc];
    const int mrow = (lane >> 4) * 4;
#pragma unroll
    for (int j = 0; j < 4; ++j) {
        int px = half * 16 + mrow + j;
        int ij = i0 * W + j0 + px;
        float sacc = 0.f;
#pragma unroll
        for (int yx = 0; yx < 9; ++yx) {
            float gv = leakyf(acc[yx][j] + bn);
            sacc += gv * mask[(b * 72 + (oc >> 3) * 9 + yx) * HW + ij];
        }
        agg[(b * 64 + oc) * HW + ij] = leakyf(sacc);
    }
}

extern "C" void kernel_launch(void* const* d_in, const int* in_sizes, int n_in,
                              void* d_out, int out_size, void* d_ws,
                              size_t ws_size, hipStream_t stream) {
    const float* ref = (const float*)d_in[0];
    const float* w1 = (const float*)d_in[1];
    const float* b1 = (const float*)d_in[2];
    const float* w2 = (const float*)d_in[3];
    const float* b2 = (const float*)d_in[4];
    const float* w3 = (const float*)d_in[5];
    const float* b3 = (const float*)d_in[6];
    const float* w4 = (const float*)d_in[7];
    const float* b4 = (const float*)d_in[8];
    const float* wm = (const float*)d_in[9];
    const float* bm = (const float*)d_in[10];
    const float* wnn = (const float*)d_in[11];
    const float* bnn = (const float*)d_in[12];
    const float* wf = (const float*)d_in[13];
    const float* bf = (const float*)d_in[14];

    char* ws = (char*)d_ws;
    constexpr size_t SZ_FEA = (size_t)BATCH * 64 * HW * 4;     // 9.44 MB
    constexpr size_t SZ_MASK = (size_t)BATCH * 72 * HW * 4;    // 10.6 MB
    constexpr size_t SZ_S = (size_t)BATCH * 49 * 98 * 98 * 4;  // 7.53 MB
    constexpr size_t SZ_IDX = (size_t)BATCH * HW * 3 * 4;
    constexpr size_t SZ_WF1 = 64 * 64 * 9 * 4;
    float* A = (float*)(ws);
    float* Bt = (float*)(ws + SZ_FEA);
    float* MASK = (float*)(ws + 2 * SZ_FEA);
    float* S = (float*)(ws + 2 * SZ_FEA + SZ_MASK);
    int* IDX = (int*)(ws + 2 * SZ_FEA + SZ_MASK + SZ_S);
    float* WF1 = (float*)(ws + 2 * SZ_FEA + SZ_MASK + SZ_S + SZ_IDX);
    short* BSWZ = (short*)(ws + 2 * SZ_FEA + SZ_MASK + SZ_S + SZ_IDX + SZ_WF1);
    float* NRT = Bt;  // reuse: Bt dead after convm
    float* AGG = A;   // reuse: A dead after convm

    // weight prep
    k_fold_w1<<<144, 256, 0, stream>>>(w1, WF1);
    k_bswz<<<(54 * 36 * 64 * 8 + 255) / 256, 256, 0, stream>>>(wnn, BSWZ);

    dim3 cgrid(3, 12, BATCH * 64);
    dim3 mgrid(3, 12, BATCH * 72);

    // mask branch
    k_conv<3, 3, 1, 1, 64, 64, true><<<cgrid, 256, 0, stream>>>(ref, nullptr, WF1, b1, A);
    k_conv<3, 3, 1, 1, 64, 64, true><<<cgrid, 256, 0, stream>>>(A, nullptr, w2, b2, Bt);
    k_conv<7, 1, 3, 0, 64, 64, true><<<cgrid, 256, 0, stream>>>(Bt, nullptr, w3, b3, A);
    k_conv<1, 7, 0, 3, 64, 64, true><<<cgrid, 256, 0, stream>>>(A, nullptr, w4, b4, Bt);
    k_conv<3, 3, 1, 1, 72, 64, false><<<mgrid, 256, 0, stream>>>(Bt, nullptr, wm, bm, MASK);

    // correlation branch (channel-last)
    k_norm_t<<<(BATCH * HW + 255) / 256, 256, 0, stream>>>(ref, NRT);
    k_corr_t<<<(BATCH * 49 * 98 * 98 + 255) / 256, 256, 0, stream>>>(NRT, S);
    k_topk<<<BATCH * HW / 256, 256, 0, stream>>>(S, IDX);

    // MFMA gather-conv + mask-weighted aggregate
    k_agg_mfma<<<BATCH * HW / 32, 512, 0, stream>>>(ref, IDX, BSWZ, bnn, MASK, AGG);

    // final fusion conv: concat([ref, agg]) -> out
    k_conv<3, 3, 1, 1, 64, 128, true><<<cgrid, 256, 0, stream>>>(ref, AGG, wf, bf, (float*)d_out);
}

// Round 3
// 1117.172 us; speedup vs baseline: 2.1540x; 1.7759x over previous
//
#include <hip/hip_runtime.h>
#include <hip/hip_bf16.h>

constexpr int BATCH = 4;
constexpr int H = 96, W = 96, HW = H * W;
constexpr int NBR = 3;

using bf16x8 = __attribute__((ext_vector_type(8))) short;  // 8 bf16 in 4 VGPRs
using f32x4 = __attribute__((ext_vector_type(4))) float;

static __device__ __forceinline__ float leakyf(float x) {
    return x >= 0.f ? x : 0.1f * x;
}

static __device__ __forceinline__ short f2bf(float x) {
    __hip_bfloat16 h = __float2bfloat16(x);
    return *reinterpret_cast<short*>(&h);
}

// ---- fold w1 (in = concat([ref, ref])) to a 64-ch weight -------------------
__global__ void k_fold_w1(const float* __restrict__ w1, float* __restrict__ wf) {
    int i = blockIdx.x * 256 + threadIdx.x;
    if (i >= 64 * 64 * 9) return;
    int k = i % 9, c = (i / 9) % 64, o = i / (64 * 9);
    wf[i] = w1[(o * 128 + c) * 9 + k] + w1[(o * 128 + 64 + c) * 9 + k];
}

// ---- build W2 in MFMA-B fragment layout (K-order: k = (n*9+rs)*64 + c) -----
// Bswz[kk(54)][nn(36)][lane(64)][e(8)] bf16; k = kk*32+(lane>>4)*8+e,
//   n-col = nn*16+(lane&15) = yx*64+oc
__global__ void k_bswz(const float* __restrict__ wnn, short* __restrict__ Bswz) {
    int i = blockIdx.x * 256 + threadIdx.x;
    if (i >= 54 * 36 * 64 * 8) return;
    int e = i & 7;
    int l = (i >> 3) & 63;
    int nn = (i >> 9) % 36;
    int kk = i / (36 * 64 * 8);
    int k = kk * 32 + (l >> 4) * 8 + e;
    int ncol = nn * 16 + (l & 15);
    int yx = ncol >> 6, oc = ncol & 63;
    int y = yx / 3, x = yx % 3;
    int nrs = k >> 6, c = k & 63;
    int nb = nrs / 9, rs = nrs % 9;
    int r = rs / 3, s = rs % 3;
    int u = r - y + 1, v = s - x + 1;
    float wv = 0.f;
    if (u >= 0 && u < 3 && v >= 0 && v < 3)
        wv = wnn[((oc * 192 + nb * 64 + c) * 3 + u) * 3 + v];
    Bswz[i] = f2bf(wv);
}

// ---- generic direct conv, LDS-tiled, 4 oc per thread -----------------------
template <int KH, int KW, int PH, int PW, int OC, int IC, bool LK>
__global__ __launch_bounds__(256) void k_conv(
    const float* __restrict__ in1, const float* __restrict__ in2,
    const float* __restrict__ wt, const float* __restrict__ bs,
    float* __restrict__ out) {
    constexpr int TJ = 32, TI = 8, CH = 8, OCPT = 4;
    constexpr int LR = TI + KH - 1, LC = TJ + KW - 1;
    __shared__ float sm[CH][LR][LC];
    const int tj0 = blockIdx.x * TJ;
    const int ti0 = blockIdx.y * TI;
    const int oc0 = (blockIdx.z % (OC / OCPT)) * OCPT;
    const int b = blockIdx.z / (OC / OCPT);
    const int tid = threadIdx.x;
    const int lj = tid % TJ, li = tid / TJ;
    float acc[OCPT] = {};
    for (int cc = 0; cc < IC; cc += CH) {
        const float* src = (cc < 64) ? in1 : in2;
        const int cb = (cc < 64) ? cc : cc - 64;
        constexpr int NE = CH * LR * LC;
        __syncthreads();
        for (int e = tid; e < NE; e += 256) {
            int c = e / (LR * LC);
            int r = (e / LC) % LR;
            int col = e % LC;
            int gi = ti0 + r - PH, gj = tj0 + col - PW;
            float v = 0.f;
            if (gi >= 0 && gi < H && gj >= 0 && gj < W)
                v = src[(b * 64 + cb + c) * HW + gi * W + gj];
            sm[c][r][col] = v;
        }
        __syncthreads();
#pragma unroll
        for (int c = 0; c < CH; ++c)
#pragma unroll
            for (int u = 0; u < KH; ++u)
#pragma unroll
                for (int v = 0; v < KW; ++v) {
                    float sv = sm[c][li + u][lj + v];
#pragma unroll
                    for (int o = 0; o < OCPT; ++o)
                        acc[o] += wt[(((oc0 + o) * IC + cc + c) * KH + u) * KW + v] * sv;
                }
    }
#pragma unroll
    for (int o = 0; o < OCPT; ++o) {
        float a = acc[o] + bs[oc0 + o];
        if (LK) a = leakyf(a);
        out[(b * OC + oc0 + o) * HW + (ti0 + li) * W + (tj0 + lj)] = a;
    }
}

// ---- L2 normalize + transpose to channel-last [b][ij][64] ------------------
__global__ void k_norm_t(const float* __restrict__ in, float* __restrict__ outT) {
    int p = blockIdx.x * 256 + threadIdx.x;
    if (p >= BATCH * HW) return;
    int b = p / HW, ij = p % HW;
    const float* src = in + b * 64 * HW + ij;
    float v[64];
    float ss = 0.f;
#pragma unroll
    for (int c = 0; c < 64; ++c) {
        v[c] = src[c * HW];
        ss += v[c] * v[c];
    }
    float inv = 1.f / fmaxf(sqrtf(ss), 1e-12f);
    float* dst = outT + (size_t)p * 64;
#pragma unroll
    for (int c = 0; c < 64; ++c) dst[c] = v[c] * inv;
}

// ---- raw ref -> channel-last bf16 [b][ij][64] ------------------------------
__global__ void k_reft(const float* __restrict__ in, short* __restrict__ outT) {
    int p = blockIdx.x * 256 + threadIdx.x;
    if (p >= BATCH * HW) return;
    int b = p / HW, ij = p % HW;
    const float* src = in + b * 64 * HW + ij;
    short* dst = outT + (size_t)p * 64;
#pragma unroll
    for (int cc = 0; cc < 8; ++cc) {
        bf16x8 o;
#pragma unroll
        for (int j = 0; j < 8; ++j) o[j] = f2bf(src[(cc * 8 + j) * HW]);
        *(bf16x8*)(dst + cc * 8) = o;
    }
}

// ---- per-displacement dot map S[b][d][y][x] from channel-last features -----
__global__ void k_corr_t(const float* __restrict__ nrT, float* __restrict__ S) {
    int idx = blockIdx.x * 256 + threadIdx.x;
    if (idx >= BATCH * 49 * 98 * 98) return;
    int x = idx % 98;
    int y = (idx / 98) % 98;
    int d = (idx / (98 * 98)) % 49;
    int b = idx / (98 * 98 * 49);
    int f1i = y - 1, f1j = x - 1;
    int f2i = y + d / 7 - 4, f2j = x + d % 7 - 4;
    float r = 0.f;
    if (f1i >= 0 && f1i < H && f1j >= 0 && f1j < W && f2i >= 0 && f2i < H &&
        f2j >= 0 && f2j < W) {
        const float4* p1 =
            (const float4*)(nrT + ((size_t)b * HW + f1i * W + f1j) * 64);
        const float4* p2 =
            (const float4*)(nrT + ((size_t)b * HW + f2i * W + f2j) * 64);
#pragma unroll
        for (int c = 0; c < 16; ++c) {
            float4 a = p1[c], bb = p2[c];
            r = fmaf(a.x, bb.x, r);
            r = fmaf(a.y, bb.y, r);
            r = fmaf(a.z, bb.z, r);
            r = fmaf(a.w, bb.w, r);
        }
    }
    S[idx] = r;
}

// ---- 3x3 window-sum per displacement + top-3 (stable: strict >) ------------
__global__ void k_topk(const float* __restrict__ S, int* __restrict__ idx3) {
    int p = blockIdx.x * 256 + threadIdx.x;
    if (p >= BATCH * HW) return;
    int b = p / HW, i = (p % HW) / W, j = p % W;
    float v0 = -1e30f, v1 = -1e30f, v2 = -1e30f;
    int d0 = 0, d1 = 0, d2 = 0;
    for (int d = 0; d < 49; ++d) {
        const float* s = S + ((b * 49 + d) * 98 + i) * 98 + j;
        float v = 0.f;
#pragma unroll
        for (int u = 0; u < 3; ++u)
#pragma unroll
            for (int vv = 0; vv < 3; ++vv) v += s[u * 98 + vv];
        if (v > v0) {
            v2 = v1; d2 = d1; v1 = v0; d1 = d0; v0 = v; d0 = d;
        } else if (v > v1) {
            v2 = v1; d2 = d1; v1 = v; d1 = d;
        } else if (v > v2) {
            v2 = v; d2 = d;
        }
    }
    idx3[p * 3 + 0] = d0;
    idx3[p * 3 + 1] = d1;
    idx3[p * 3 + 2] = d2;
}

// ---- MFMA gather-conv + mask reduce ----------------------------------------
// 32 pixels/block, 8 waves. GEMM: [32 x 1728] x [1728 x 576].
// K-order k=(n*9+rs)*64+c so a patch row = 64 contiguous bf16 in channel-last
// ref. A staged in LDS fragment layout via b128 writes, XOR-swizzled
// (byte ^= ((byte>>8)&7)<<4) on both write and read.
__global__ __launch_bounds__(512) void k_agg_mfma(
    const short* __restrict__ refT, const int* __restrict__ idx3,
    const short* __restrict__ Bswz, const float* __restrict__ bnn,
    const float* __restrict__ mask, float* __restrict__ agg) {
    constexpr int PX = 32;
    __shared__ short A_lds[2 * 54 * 64 * 8];  // 110,592 B
    __shared__ int sd[PX][NBR];
    const int p0 = blockIdx.x * PX;
    const int b = p0 / HW;
    const int i0 = (p0 % HW) / W;
    const int j0 = p0 % W;
    const int tid = threadIdx.x;
    if (tid < PX * NBR)
        sd[tid / NBR][tid % NBR] = idx3[(p0 + tid / NBR) * NBR + tid % NBR];
    __syncthreads();
    // gather: unit = (px, n, rs, oct) -> one 16-B channel-octet
    for (int u = tid; u < PX * NBR * 9 * 8; u += 512) {
        int oct = u & 7;
        int q = u >> 3;
        int rs = q % 9;
        int w2 = q / 9;
        int n = w2 % 3;
        int px = w2 / 3;
        int d = sd[px][n];
        int gi = i0 + d / 7 + rs / 3 - 4;
        int gj = j0 + px + d % 7 + rs % 3 - 4;
        bf16x8 val = {};
        if (gi >= 0 && gi < H && gj >= 0 && gj < W)
            val = *(const bf16x8*)(refT + ((size_t)(b * HW + gi * W + gj)) * 64 +
                                   oct * 8);
        int kb = (n * 9 + rs) * 64 + oct * 8;
        int chunk = (((px >> 4) * 54 + (kb >> 5)) << 6) + (((kb >> 3) & 3) << 4) +
                    (px & 15);
        int byte = chunk << 4;
        byte ^= ((byte >> 8) & 7) << 4;
        *(bf16x8*)((char*)A_lds + byte) = val;
    }
    __syncthreads();
    const int wave = tid >> 6;
    const int lane = tid & 63;
    const int w = wave & 3;      // oc slice
    const int half = wave >> 2;  // pixel group
    f32x4 acc[9] = {};
    const short* Bp = Bswz + ((size_t)w * 64 + lane) * 8;
    const int abase = ((half * 54) * 64 + lane) << 4;
    for (int kk = 0; kk < 54; ++kk) {
        int ab = abase + (kk << 10);
        ab ^= ((ab >> 8) & 7) << 4;
        bf16x8 a = *(const bf16x8*)((char*)A_lds + ab);
        const short* bp = Bp + (size_t)kk * 36 * 64 * 8;
#pragma unroll
        for (int yx = 0; yx < 9; ++yx) {
            bf16x8 bv = *(const bf16x8*)(bp + yx * 4 * 64 * 8);
            acc[yx] = __builtin_amdgcn_mfma_f32_16x16x32_bf16(a, bv, acc[yx], 0, 0, 0);
        }
    }
    // epilogue: bias -> leaky -> mask-weighted sum over 9 positions -> leaky
    const int oc = w * 16 + (lane & 15);
    const float bn = bnn[oc];
    const int mrow = (lane >> 4) * 4;
#pragma unroll
    for (int j = 0; j < 4; ++j) {
        int px = half * 16 + mrow + j;
        int ij = i0 * W + j0 + px;
        float sacc = 0.f;
#pragma unroll
        for (int yx = 0; yx < 9; ++yx) {
            float gv = leakyf(acc[yx][j] + bn);
            sacc += gv * mask[(b * 72 + (oc >> 3) * 9 + yx) * HW + ij];
        }
        agg[(b * 64 + oc) * HW + ij] = leakyf(sacc);
    }
}

extern "C" void kernel_launch(void* const* d_in, const int* in_sizes, int n_in,
                              void* d_out, int out_size, void* d_ws,
                              size_t ws_size, hipStream_t stream) {
    const float* ref = (const float*)d_in[0];
    const float* w1 = (const float*)d_in[1];
    const float* b1 = (const float*)d_in[2];
    const float* w2 = (const float*)d_in[3];
    const float* b2 = (const float*)d_in[4];
    const float* w3 = (const float*)d_in[5];
    const float* b3 = (const float*)d_in[6];
    const float* w4 = (const float*)d_in[7];
    const float* b4 = (const float*)d_in[8];
    const float* wm = (const float*)d_in[9];
    const float* bm = (const float*)d_in[10];
    const float* wnn = (const float*)d_in[11];
    const float* bnn = (const float*)d_in[12];
    const float* wf = (const float*)d_in[13];
    const float* bf = (const float*)d_in[14];

    char* ws = (char*)d_ws;
    constexpr size_t SZ_FEA = (size_t)BATCH * 64 * HW * 4;     // 9.44 MB
    constexpr size_t SZ_MASK = (size_t)BATCH * 72 * HW * 4;    // 10.6 MB
    constexpr size_t SZ_S = (size_t)BATCH * 49 * 98 * 98 * 4;  // 7.53 MB
    constexpr size_t SZ_IDX = (size_t)BATCH * HW * 3 * 4;
    constexpr size_t SZ_WF1 = 64 * 64 * 9 * 4;
    float* A = (float*)(ws);
    float* Bt = (float*)(ws + SZ_FEA);
    float* MASK = (float*)(ws + 2 * SZ_FEA);
    float* S = (float*)(ws + 2 * SZ_FEA + SZ_MASK);
    int* IDX = (int*)(ws + 2 * SZ_FEA + SZ_MASK + SZ_S);
    float* WF1 = (float*)(ws + 2 * SZ_FEA + SZ_MASK + SZ_S + SZ_IDX);
    short* BSWZ = (short*)(ws + 2 * SZ_FEA + SZ_MASK + SZ_S + SZ_IDX + SZ_WF1);
    float* NRT = Bt;          // reuse: Bt dead after convm
    float* AGG = A;           // reuse: A dead after conv4
    short* REFT = (short*)S;  // reuse: S dead after k_topk (4.7 MB <= 7.53 MB)

    // weight prep
    k_fold_w1<<<144, 256, 0, stream>>>(w1, WF1);
    k_bswz<<<(54 * 36 * 64 * 8 + 255) / 256, 256, 0, stream>>>(wnn, BSWZ);

    dim3 cgrid(3, 12, BATCH * 16);
    dim3 mgrid(3, 12, BATCH * 18);

    // mask branch
    k_conv<3, 3, 1, 1, 64, 64, true><<<cgrid, 256, 0, stream>>>(ref, nullptr, WF1, b1, A);
    k_conv<3, 3, 1, 1, 64, 64, true><<<cgrid, 256, 0, stream>>>(A, nullptr, w2, b2, Bt);
    k_conv<7, 1, 3, 0, 64, 64, true><<<cgrid, 256, 0, stream>>>(Bt, nullptr, w3, b3, A);
    k_conv<1, 7, 0, 3, 64, 64, true><<<cgrid, 256, 0, stream>>>(A, nullptr, w4, b4, Bt);
    k_conv<3, 3, 1, 1, 72, 64, false><<<mgrid, 256, 0, stream>>>(Bt, nullptr, wm, bm, MASK);

    // correlation branch (channel-last)
    k_norm_t<<<(BATCH * HW + 255) / 256, 256, 0, stream>>>(ref, NRT);
    k_corr_t<<<(BATCH * 49 * 98 * 98 + 255) / 256, 256, 0, stream>>>(NRT, S);
    k_topk<<<BATCH * HW / 256, 256, 0, stream>>>(S, IDX);

    // channel-last bf16 ref for the gather (into dead S region)
    k_reft<<<(BATCH * HW + 255) / 256, 256, 0, stream>>>(ref, REFT);

    // MFMA gather-conv + mask-weighted aggregate
    k_agg_mfma<<<BATCH * HW / 32, 512, 0, stream>>>(REFT, IDX, BSWZ, bnn, MASK, AGG);

    // final fusion conv: concat([ref, agg]) -> out
    k_conv<3, 3, 1, 1, 64, 128, true><<<cgrid, 256, 0, stream>>>(ref, AGG, wf, bf, (float*)d_out);
}

// Round 4
// 362.747 us; speedup vs baseline: 6.6339x; 3.0798x over previous
//
#include <hip/hip_runtime.h>
#include <hip/hip_bf16.h>

constexpr int BATCH = 4;
constexpr int H = 96, W = 96, HW = H * W;
constexpr int NBR = 3;

using bf16x8 = __attribute__((ext_vector_type(8))) short;  // 8 bf16 in 4 VGPRs
using f32x4 = __attribute__((ext_vector_type(4))) float;

static __device__ __forceinline__ float leakyf(float x) {
    return x >= 0.f ? x : 0.1f * x;
}

static __device__ __forceinline__ short f2bf(float x) {
    __hip_bfloat16 h = __float2bfloat16(x);
    return *reinterpret_cast<short*>(&h);
}

// ---- fused: ref NCHW fp32 -> REFT (bf16 ch-last) + NRT (normalized fp32) ---
__global__ __launch_bounds__(256) void k_pre(const float* __restrict__ ref,
                                             short* __restrict__ reft,
                                             float* __restrict__ nrt) {
    int p = blockIdx.x * 256 + threadIdx.x;
    if (p >= BATCH * HW) return;
    int b = p / HW, ij = p % HW;
    const float* src = ref + b * 64 * HW + ij;
    float v[64];
    float ss = 0.f;
#pragma unroll
    for (int c = 0; c < 64; ++c) {
        v[c] = src[c * HW];
        ss += v[c] * v[c];
    }
    float inv = 1.f / fmaxf(sqrtf(ss), 1e-12f);
    short* rd = reft + (size_t)p * 64;
#pragma unroll
    for (int cc = 0; cc < 8; ++cc) {
        bf16x8 o;
#pragma unroll
        for (int j = 0; j < 8; ++j) o[j] = f2bf(v[cc * 8 + j]);
        *(bf16x8*)(rd + cc * 8) = o;
    }
    float* nd = nrt + (size_t)p * 64;
#pragma unroll
    for (int c = 0; c < 64; ++c) nd[c] = v[c] * inv;
}

// ---- pack conv weights (OIHW fp32) into MFMA-B fragment layout -------------
// dst[tap][kk][nt][lane][e]; ic = kk*32+(l>>4)*8+e, oc = nt*16+(l&15)
__global__ void k_prep(const float* __restrict__ src, short* __restrict__ dst,
                       int OC, int ICt, int ICsrc, int KH, int KW, int NT,
                       int fold, int total) {
    int i = blockIdx.x * 256 + threadIdx.x;
    if (i >= total) return;
    int e = i & 7, l = (i >> 3) & 63;
    int rest = i >> 9;
    int nt = rest % NT;
    rest /= NT;
    int ICK = ICt >> 5;
    int kk = rest % ICK;
    int tap = rest / ICK;
    int ic = kk * 32 + (l >> 4) * 8 + e;
    int oc = nt * 16 + (l & 15);
    int u = tap / KW, v = tap % KW;
    float val = 0.f;
    if (oc < OC) {
        val = src[((oc * ICsrc + ic) * KH + u) * KW + v];
        if (fold) val += src[((oc * ICsrc + 64 + ic) * KH + u) * KW + v];
    }
    dst[i] = f2bf(val);
}

// ---- channel-last bf16 implicit-GEMM conv ----------------------------------
// tile 8x32 px, 8 waves x (2 Mtiles x NT Ntiles). X staged in LDS (XOR swz),
// B staged in LDS when it fits (BLDS), else streamed from L2.
// OMODE 0: bf16 ch-last + leaky; 1: fp32 ch-last 72 (no act); 2: NCHW fp32 + leaky
template <int KH, int KW, int IC, int OC, int OMODE, bool BLDS>
__global__ __launch_bounds__(512) void k_cmfma(
    const short* __restrict__ inA, const short* __restrict__ inB,
    const short* __restrict__ Bp, const float* __restrict__ bias,
    void* __restrict__ outp) {
    constexpr int TI = 8, TJ = 32;
    constexpr int PH = (KH - 1) / 2, PW = (KW - 1) / 2;
    constexpr int LR = TI + KH - 1, LC = TJ + KW - 1;
    constexpr int ICB = IC * 2;
    constexpr int LS = (ICB == 128) ? 7 : 8;
    constexpr int ICK = IC / 32;
    constexpr int NT = (OC + 15) / 16;
    constexpr int TAPS = KH * KW;
    constexpr int NOCT = ICB / 16;
    __shared__ char Xs[LR * LC * ICB];
    __shared__ short Bs[BLDS ? TAPS * ICK * NT * 512 : 8];
    const int tj0 = blockIdx.x * TJ, ti0 = blockIdx.y * TI, b = blockIdx.z;
    const int tid = threadIdx.x;
    if (BLDS) {
        for (int u2 = tid; u2 < TAPS * ICK * NT * 64; u2 += 512)
            ((bf16x8*)Bs)[u2] = ((const bf16x8*)Bp)[u2];
    }
    for (int u2 = tid; u2 < LR * LC * NOCT; u2 += 512) {
        int oct = u2 % NOCT;
        int hp = u2 / NOCT;
        int hr = hp / LC, hc = hp % LC;
        int gi = ti0 + hr - PH, gj = tj0 + hc - PW;
        bf16x8 v = {};
        if (gi >= 0 && gi < H && gj >= 0 && gj < W) {
            const short* s = (oct < 8) ? inA : inB;
            v = *(const bf16x8*)(s + (size_t)(b * HW + gi * W + gj) * 64 +
                                 (oct & 7) * 8);
        }
        int byte = hp * ICB + oct * 16;
        byte ^= ((byte >> LS) & 7) << 4;
        *(bf16x8*)(Xs + byte) = v;
    }
    __syncthreads();
    const int wave = tid >> 6, l = tid & 63;
    const int r = l & 15, q = l >> 4;
    const int mt0 = wave * 2;
    int p0 = mt0 * 16 + r, p1 = p0 + 16;
    int li0 = p0 >> 5, lj0 = p0 & 31, li1 = p1 >> 5, lj1 = p1 & 31;
    f32x4 acc[2][NT] = {};
#pragma unroll
    for (int t = 0; t < TAPS; ++t) {
        const int u = t / KW, v = t % KW;
        int hp0 = (li0 + u) * LC + (lj0 + v);
        int hp1 = (li1 + u) * LC + (lj1 + v);
#pragma unroll
        for (int kk = 0; kk < ICK; ++kk) {
            int ab0 = hp0 * ICB + kk * 64 + q * 16;
            ab0 ^= ((ab0 >> LS) & 7) << 4;
            int ab1 = hp1 * ICB + kk * 64 + q * 16;
            ab1 ^= ((ab1 >> LS) & 7) << 4;
            bf16x8 a0 = *(const bf16x8*)(Xs + ab0);
            bf16x8 a1 = *(const bf16x8*)(Xs + ab1);
            const short* bbase =
                (BLDS ? (const short*)Bs : Bp) + (t * ICK + kk) * NT * 512 + l * 8;
#pragma unroll
            for (int nt = 0; nt < NT; ++nt) {
                bf16x8 bv = *(const bf16x8*)(bbase + nt * 512);
                acc[0][nt] =
                    __builtin_amdgcn_mfma_f32_16x16x32_bf16(a0, bv, acc[0][nt], 0, 0, 0);
                acc[1][nt] =
                    __builtin_amdgcn_mfma_f32_16x16x32_bf16(a1, bv, acc[1][nt], 0, 0, 0);
            }
        }
    }
    const int col = l & 15;
#pragma unroll
    for (int mt = 0; mt < 2; ++mt)
#pragma unroll
        for (int nt = 0; nt < NT; ++nt) {
            int oc = nt * 16 + col;
            float bs = (oc < OC) ? bias[oc] : 0.f;
#pragma unroll
            for (int j = 0; j < 4; ++j) {
                int p = (mt0 + mt) * 16 + q * 4 + j;
                int gi = ti0 + (p >> 5), gj = tj0 + (p & 31);
                float val = acc[mt][nt][j] + bs;
                if (OMODE == 0) {
                    val = leakyf(val);
                    *((short*)outp + (size_t)(b * HW + gi * W + gj) * 64 + oc) =
                        f2bf(val);
                } else if (OMODE == 1) {
                    if (oc < 72)
                        *((float*)outp + (size_t)(b * HW + gi * W + gj) * 72 + oc) = val;
                } else {
                    val = leakyf(val);
                    *((float*)outp + (size_t)(b * 64 + oc) * HW + gi * W + gj) = val;
                }
            }
        }
}

// ---- per-displacement dot map S[b][d][y][x] from channel-last features -----
__global__ void k_corr_t(const float* __restrict__ nrT, float* __restrict__ S) {
    int idx = blockIdx.x * 256 + threadIdx.x;
    if (idx >= BATCH * 49 * 98 * 98) return;
    int x = idx % 98;
    int y = (idx / 98) % 98;
    int d = (idx / (98 * 98)) % 49;
    int b = idx / (98 * 98 * 49);
    int f1i = y - 1, f1j = x - 1;
    int f2i = y + d / 7 - 4, f2j = x + d % 7 - 4;
    float r = 0.f;
    if (f1i >= 0 && f1i < H && f1j >= 0 && f1j < W && f2i >= 0 && f2i < H &&
        f2j >= 0 && f2j < W) {
        const float4* p1 =
            (const float4*)(nrT + ((size_t)b * HW + f1i * W + f1j) * 64);
        const float4* p2 =
            (const float4*)(nrT + ((size_t)b * HW + f2i * W + f2j) * 64);
#pragma unroll
        for (int c = 0; c < 16; ++c) {
            float4 a = p1[c], bb = p2[c];
            r = fmaf(a.x, bb.x, r);
            r = fmaf(a.y, bb.y, r);
            r = fmaf(a.z, bb.z, r);
            r = fmaf(a.w, bb.w, r);
        }
    }
    S[idx] = r;
}

// ---- 3x3 window-sum per displacement + top-3 (stable: strict >) ------------
__global__ void k_topk(const float* __restrict__ S, int* __restrict__ idx3) {
    int p = blockIdx.x * 256 + threadIdx.x;
    if (p >= BATCH * HW) return;
    int b = p / HW, i = (p % HW) / W, j = p % W;
    float v0 = -1e30f, v1 = -1e30f, v2 = -1e30f;
    int d0 = 0, d1 = 0, d2 = 0;
    for (int d = 0; d < 49; ++d) {
        const float* s = S + ((b * 49 + d) * 98 + i) * 98 + j;
        float v = 0.f;
#pragma unroll
        for (int u = 0; u < 3; ++u)
#pragma unroll
            for (int vv = 0; vv < 3; ++vv) v += s[u * 98 + vv];
        if (v > v0) {
            v2 = v1; d2 = d1; v1 = v0; d1 = d0; v0 = v; d0 = d;
        } else if (v > v1) {
            v2 = v1; d2 = d1; v1 = v; d1 = d;
        } else if (v > v2) {
            v2 = v; d2 = d;
        }
    }
    idx3[p * 3 + 0] = d0;
    idx3[p * 3 + 1] = d1;
    idx3[p * 3 + 2] = d2;
}

// ---- build W2 in MFMA-B fragment layout (K-order: k = (n*9+rs)*64 + c) -----
__global__ void k_bswz(const float* __restrict__ wnn, short* __restrict__ Bswz) {
    int i = blockIdx.x * 256 + threadIdx.x;
    if (i >= 54 * 36 * 64 * 8) return;
    int e = i & 7;
    int l = (i >> 3) & 63;
    int nn = (i >> 9) % 36;
    int kk = i / (36 * 64 * 8);
    int k = kk * 32 + (l >> 4) * 8 + e;
    int ncol = nn * 16 + (l & 15);
    int yx = ncol >> 6, oc = ncol & 63;
    int y = yx / 3, x = yx % 3;
    int nrs = k >> 6, c = k & 63;
    int nb = nrs / 9, rs = nrs % 9;
    int r = rs / 3, s = rs % 3;
    int u = r - y + 1, v = s - x + 1;
    float wv = 0.f;
    if (u >= 0 && u < 3 && v >= 0 && v < 3)
        wv = wnn[((oc * 192 + nb * 64 + c) * 3 + u) * 3 + v];
    Bswz[i] = f2bf(wv);
}

// ---- MFMA gather-conv + mask reduce (valid-block skip) ---------------------
__global__ __launch_bounds__(512) void k_agg_mfma(
    const short* __restrict__ refT, const int* __restrict__ idx3,
    const short* __restrict__ Bswz, const float* __restrict__ bnn,
    const float* __restrict__ maskT, short* __restrict__ agg) {
    constexpr int PX = 32;
    __shared__ short A_lds[2 * 54 * 64 * 8];  // 110,592 B
    __shared__ int sd[PX][NBR];
    const int p0 = blockIdx.x * PX;
    const int b = p0 / HW;
    const int i0 = (p0 % HW) / W;
    const int j0 = p0 % W;
    const int tid = threadIdx.x;
    if (tid < PX * NBR)
        sd[tid / NBR][tid % NBR] = idx3[(p0 + tid / NBR) * NBR + tid % NBR];
    __syncthreads();
    for (int u = tid; u < PX * NBR * 9 * 8; u += 512) {
        int oct = u & 7;
        int q = u >> 3;
        int rs = q % 9;
        int w2 = q / 9;
        int n = w2 % 3;
        int px = w2 / 3;
        int d = sd[px][n];
        int gi = i0 + d / 7 + rs / 3 - 4;
        int gj = j0 + px + d % 7 + rs % 3 - 4;
        bf16x8 val = {};
        if (gi >= 0 && gi < H && gj >= 0 && gj < W)
            val = *(const bf16x8*)(refT + ((size_t)(b * HW + gi * W + gj)) * 64 +
                                   oct * 8);
        int kb = (n * 9 + rs) * 64 + oct * 8;
        int chunk = (((px >> 4) * 54 + (kb >> 5)) << 6) + (((kb >> 3) & 3) << 4) +
                    (px & 15);
        int byte = chunk << 4;
        byte ^= ((byte >> 8) & 7) << 4;
        *(bf16x8*)((char*)A_lds + byte) = val;
    }
    __syncthreads();
    const int wave = tid >> 6;
    const int lane = tid & 63;
    const int w = wave & 3;      // oc slice
    const int half = wave >> 2;  // pixel group
    f32x4 acc[9] = {};
    const short* Bp0 = Bswz + ((size_t)w * 64 + lane) * 8;
    const int abase = ((half * 54) * 64 + lane) << 4;
    for (int n = 0; n < 3; ++n) {
#pragma unroll
        for (int rs = 0; rs < 9; ++rs) {
#pragma unroll
            for (int h2 = 0; h2 < 2; ++h2) {
                const int kk = (n * 9 + rs) * 2 + h2;
                int ab = abase + (kk << 10);
                ab ^= ((ab >> 8) & 7) << 4;
                bf16x8 a = *(const bf16x8*)((char*)A_lds + ab);
#pragma unroll
                for (int yx = 0; yx < 9; ++yx) {
                    if (rs / 3 - yx / 3 <= 1 && yx / 3 - rs / 3 <= 1 &&
                        rs % 3 - yx % 3 <= 1 && yx % 3 - rs % 3 <= 1) {
                        bf16x8 bv =
                            *(const bf16x8*)(Bp0 + ((size_t)kk * 36 + yx * 4) * 512);
                        acc[yx] = __builtin_amdgcn_mfma_f32_16x16x32_bf16(a, bv,
                                                                          acc[yx], 0, 0, 0);
                    }
                }
            }
        }
    }
    const int oc = w * 16 + (lane & 15);
    const float bn = bnn[oc];
    const int mrow = (lane >> 4) * 4;
#pragma unroll
    for (int j = 0; j < 4; ++j) {
        int px = half * 16 + mrow + j;
        int ij = i0 * W + j0 + px;
        const float* mb = maskT + (size_t)(b * HW + ij) * 72 + (oc >> 3) * 9;
        float sacc = 0.f;
#pragma unroll
        for (int yx = 0; yx < 9; ++yx) {
            float gv = leakyf(acc[yx][j] + bn);
            sacc += gv * mb[yx];
        }
        agg[(size_t)(b * HW + ij) * 64 + oc] = f2bf(leakyf(sacc));
    }
}

extern "C" void kernel_launch(void* const* d_in, const int* in_sizes, int n_in,
                              void* d_out, int out_size, void* d_ws,
                              size_t ws_size, hipStream_t stream) {
    const float* ref = (const float*)d_in[0];
    const float* w1 = (const float*)d_in[1];
    const float* b1 = (const float*)d_in[2];
    const float* w2 = (const float*)d_in[3];
    const float* b2 = (const float*)d_in[4];
    const float* w3 = (const float*)d_in[5];
    const float* b3 = (const float*)d_in[6];
    const float* w4 = (const float*)d_in[7];
    const float* b4 = (const float*)d_in[8];
    const float* wm = (const float*)d_in[9];
    const float* bm = (const float*)d_in[10];
    const float* wnn = (const float*)d_in[11];
    const float* bnn = (const float*)d_in[12];
    const float* wf = (const float*)d_in[13];
    const float* bf = (const float*)d_in[14];

    char* ws = (char*)d_ws;
    constexpr size_t O_NRT = 0;
    constexpr size_t O_S = O_NRT + (size_t)BATCH * HW * 64 * 4;   // 9,437,184
    constexpr size_t O_REFT = O_S + (size_t)BATCH * 49 * 98 * 98 * 4;
    constexpr size_t O_X1 = O_REFT + (size_t)BATCH * HW * 64 * 2;
    constexpr size_t O_X2 = O_X1 + (size_t)BATCH * HW * 64 * 2;
    constexpr size_t O_MASKT = O_X2 + (size_t)BATCH * HW * 64 * 2;
    constexpr size_t O_IDX = O_MASKT + (size_t)BATCH * HW * 72 * 4;
    constexpr size_t O_P1 = O_IDX + (size_t)BATCH * HW * 3 * 4;
    constexpr size_t O_P2 = O_P1 + 73728 * 2;
    constexpr size_t O_P3 = O_P2 + 73728 * 2;
    constexpr size_t O_P4 = O_P3 + 28672 * 2;
    constexpr size_t O_PM = O_P4 + 28672 * 2;
    constexpr size_t O_PF = O_PM + 46080 * 2;

    float* NRT = (float*)(ws + O_NRT);
    float* S = (float*)(ws + O_S);
    short* BSWZ = (short*)(ws + O_S);  // aliased: written after topk
    short* REFT = (short*)(ws + O_REFT);
    short* X1 = (short*)(ws + O_X1);
    short* X2 = (short*)(ws + O_X2);
    float* MASKT = (float*)(ws + O_MASKT);
    int* IDX = (int*)(ws + O_IDX);
    short* P1 = (short*)(ws + O_P1);
    short* P2 = (short*)(ws + O_P2);
    short* P3 = (short*)(ws + O_P3);
    short* P4 = (short*)(ws + O_P4);
    short* PM = (short*)(ws + O_PM);
    short* PF = (short*)(ws + O_PF);

    // input prep + weight packing
    k_pre<<<(BATCH * HW + 255) / 256, 256, 0, stream>>>(ref, REFT, NRT);
    k_prep<<<144, 256, 0, stream>>>(w1, P1, 64, 64, 128, 3, 3, 4, 1, 36864);
    k_prep<<<144, 256, 0, stream>>>(w2, P2, 64, 64, 64, 3, 3, 4, 0, 36864);
    k_prep<<<112, 256, 0, stream>>>(w3, P3, 64, 64, 64, 7, 1, 4, 0, 28672);
    k_prep<<<112, 256, 0, stream>>>(w4, P4, 64, 64, 64, 1, 7, 4, 0, 28672);
    k_prep<<<180, 256, 0, stream>>>(wm, PM, 72, 64, 64, 3, 3, 5, 0, 46080);
    k_prep<<<288, 256, 0, stream>>>(wf, PF, 64, 128, 128, 3, 3, 4, 0, 73728);

    dim3 cgrid(3, 12, BATCH);
    // mask branch (MFMA convs, bf16 channel-last chain)
    k_cmfma<3, 3, 64, 64, 0, true><<<cgrid, 512, 0, stream>>>(REFT, nullptr, P1, b1, X1);
    k_cmfma<3, 3, 64, 64, 0, true><<<cgrid, 512, 0, stream>>>(X1, nullptr, P2, b2, X2);
    k_cmfma<7, 1, 64, 64, 0, true><<<cgrid, 512, 0, stream>>>(X2, nullptr, P3, b3, X1);
    k_cmfma<1, 7, 64, 64, 0, true><<<cgrid, 512, 0, stream>>>(X1, nullptr, P4, b4, X2);
    k_cmfma<3, 3, 64, 72, 1, true><<<cgrid, 512, 0, stream>>>(X2, nullptr, PM, bm, MASKT);

    // correlation branch
    k_corr_t<<<(BATCH * 49 * 98 * 98 + 255) / 256, 256, 0, stream>>>(NRT, S);
    k_topk<<<BATCH * HW / 256, 256, 0, stream>>>(S, IDX);

    // W2 pack (into dead S region)
    k_bswz<<<(54 * 36 * 64 * 8 + 255) / 256, 256, 0, stream>>>(wnn, BSWZ);

    // MFMA gather-conv + mask-weighted aggregate -> X1 (bf16 ch-last)
    k_agg_mfma<<<BATCH * HW / 32, 512, 0, stream>>>(REFT, IDX, BSWZ, bnn, MASKT, X1);

    // final fusion conv: concat([ref, agg]) -> NCHW fp32 out
    k_cmfma<3, 3, 128, 64, 2, false><<<cgrid, 512, 0, stream>>>(REFT, X1, PF, bf, d_out);
}

// Round 5
// 304.634 us; speedup vs baseline: 7.8994x; 1.1908x over previous
//
#include <hip/hip_runtime.h>
#include <hip/hip_bf16.h>

constexpr int BATCH = 4;
constexpr int H = 96, W = 96, HW = H * W;
constexpr int NBR = 3;

using bf16x8 = __attribute__((ext_vector_type(8))) short;  // 8 bf16 in 4 VGPRs
using f32x4 = __attribute__((ext_vector_type(4))) float;

static __device__ __forceinline__ float leakyf(float x) {
    return x >= 0.f ? x : 0.1f * x;
}

static __device__ __forceinline__ short f2bf(float x) {
    __hip_bfloat16 h = __float2bfloat16(x);
    return *reinterpret_cast<short*>(&h);
}

static __device__ __forceinline__ float bf2f(short s) {
    __hip_bfloat16 h = *reinterpret_cast<__hip_bfloat16*>(&s);
    return __bfloat162float(h);
}

// ---- fused: ref NCHW fp32 -> REFT (bf16 ch-last) + NRT (normalized fp32) ---
__global__ __launch_bounds__(256) void k_pre(const float* __restrict__ ref,
                                             short* __restrict__ reft,
                                             float* __restrict__ nrt) {
    int p = blockIdx.x * 256 + threadIdx.x;
    if (p >= BATCH * HW) return;
    int b = p / HW, ij = p % HW;
    const float* src = ref + b * 64 * HW + ij;
    float v[64];
    float ss = 0.f;
#pragma unroll
    for (int c = 0; c < 64; ++c) {
        v[c] = src[c * HW];
        ss += v[c] * v[c];
    }
    float inv = 1.f / fmaxf(sqrtf(ss), 1e-12f);
    short* rd = reft + (size_t)p * 64;
#pragma unroll
    for (int cc = 0; cc < 8; ++cc) {
        bf16x8 o;
#pragma unroll
        for (int j = 0; j < 8; ++j) o[j] = f2bf(v[cc * 8 + j]);
        *(bf16x8*)(rd + cc * 8) = o;
    }
    float* nd = nrt + (size_t)p * 64;
#pragma unroll
    for (int c = 0; c < 64; ++c) nd[c] = v[c] * inv;
}

// ---- pack conv weights (OIHW fp32) into MFMA-B fragment layout -------------
// dst[tap][kk][nt][lane][e]; ic = kk*32+(l>>4)*8+e, oc = nt*16+(l&15)
__global__ void k_prep(const float* __restrict__ src, short* __restrict__ dst,
                       int OC, int ICt, int ICsrc, int KH, int KW, int NT,
                       int fold, int total) {
    int i = blockIdx.x * 256 + threadIdx.x;
    if (i >= total) return;
    int e = i & 7, l = (i >> 3) & 63;
    int rest = i >> 9;
    int nt = rest % NT;
    rest /= NT;
    int ICK = ICt >> 5;
    int kk = rest % ICK;
    int tap = rest / ICK;
    int ic = kk * 32 + (l >> 4) * 8 + e;
    int oc = nt * 16 + (l & 15);
    int u = tap / KW, v = tap % KW;
    float val = 0.f;
    if (oc < OC) {
        val = src[((oc * ICsrc + ic) * KH + u) * KW + v];
        if (fold) val += src[((oc * ICsrc + 64 + ic) * KH + u) * KW + v];
    }
    dst[i] = f2bf(val);
}

// ---- channel-last bf16 implicit-GEMM conv ----------------------------------
// tile 8x32 px, 8 waves x (2 Mtiles x NTb Ntiles). X staged in LDS (XOR swz),
// B staged in LDS when BLDS, else streamed. NSPL: split OC across blocks.
// OMODE 0: bf16 ch-last + leaky; 1: bf16 ch-last 72 (no act); 2: NCHW fp32 + leaky
template <int KH, int KW, int IC, int OC, int OMODE, bool BLDS, int NSPL>
__global__ __launch_bounds__(512) void k_cmfma(
    const short* __restrict__ inA, const short* __restrict__ inB,
    const short* __restrict__ Bp, const float* __restrict__ bias,
    void* __restrict__ outp) {
    constexpr int TI = 8, TJ = 32;
    constexpr int PH = (KH - 1) / 2, PW = (KW - 1) / 2;
    constexpr int LR = TI + KH - 1, LC = TJ + KW - 1;
    constexpr int ICB = IC * 2;
    constexpr int LS = (ICB == 128) ? 7 : 8;
    constexpr int ICK = IC / 32;
    constexpr int NTF = (OC + 15) / 16;
    constexpr int NTb = NTF / NSPL;
    constexpr int TAPS = KH * KW;
    constexpr int NOCT = ICB / 16;
    __shared__ char Xs[LR * LC * ICB];
    __shared__ short Bs[BLDS ? TAPS * ICK * NTb * 512 : 8];
    const int tj0 = blockIdx.x * TJ, ti0 = blockIdx.y * TI;
    const int b = blockIdx.z / NSPL;
    const int nt0 = (blockIdx.z % NSPL) * NTb;
    const int tid = threadIdx.x;
    if (BLDS) {
        for (int u2 = tid; u2 < TAPS * ICK * NTb * 64; u2 += 512) {
            int l2 = u2 & 63;
            int rest = u2 >> 6;
            int nt = rest % NTb;
            int qk = rest / NTb;
            ((bf16x8*)Bs)[u2] = ((const bf16x8*)Bp)[(qk * NTF + nt0 + nt) * 64 + l2];
        }
    }
    for (int u2 = tid; u2 < LR * LC * NOCT; u2 += 512) {
        int oct = u2 % NOCT;
        int hp = u2 / NOCT;
        int hr = hp / LC, hc = hp % LC;
        int gi = ti0 + hr - PH, gj = tj0 + hc - PW;
        bf16x8 v = {};
        if (gi >= 0 && gi < H && gj >= 0 && gj < W) {
            const short* s = (oct < 8) ? inA : inB;
            v = *(const bf16x8*)(s + (size_t)(b * HW + gi * W + gj) * 64 +
                                 (oct & 7) * 8);
        }
        int byte = hp * ICB + oct * 16;
        byte ^= ((byte >> LS) & 7) << 4;
        *(bf16x8*)(Xs + byte) = v;
    }
    __syncthreads();
    const int wave = tid >> 6, l = tid & 63;
    const int r = l & 15, q = l >> 4;
    const int mt0 = wave * 2;
    int p0 = mt0 * 16 + r, p1 = p0 + 16;
    int li0 = p0 >> 5, lj0 = p0 & 31, li1 = p1 >> 5, lj1 = p1 & 31;
    f32x4 acc[2][NTb] = {};
#pragma unroll
    for (int t = 0; t < TAPS; ++t) {
        const int u = t / KW, v = t % KW;
        int hp0 = (li0 + u) * LC + (lj0 + v);
        int hp1 = (li1 + u) * LC + (lj1 + v);
#pragma unroll
        for (int kk = 0; kk < ICK; ++kk) {
            int ab0 = hp0 * ICB + kk * 64 + q * 16;
            ab0 ^= ((ab0 >> LS) & 7) << 4;
            int ab1 = hp1 * ICB + kk * 64 + q * 16;
            ab1 ^= ((ab1 >> LS) & 7) << 4;
            bf16x8 a0 = *(const bf16x8*)(Xs + ab0);
            bf16x8 a1 = *(const bf16x8*)(Xs + ab1);
            const short* bbase =
                BLDS ? (const short*)Bs + (t * ICK + kk) * NTb * 512 + l * 8
                     : Bp + ((t * ICK + kk) * NTF + nt0) * 512 + l * 8;
#pragma unroll
            for (int nt = 0; nt < NTb; ++nt) {
                bf16x8 bv = *(const bf16x8*)(bbase + nt * 512);
                acc[0][nt] =
                    __builtin_amdgcn_mfma_f32_16x16x32_bf16(a0, bv, acc[0][nt], 0, 0, 0);
                acc[1][nt] =
                    __builtin_amdgcn_mfma_f32_16x16x32_bf16(a1, bv, acc[1][nt], 0, 0, 0);
            }
        }
    }
    const int col = l & 15;
#pragma unroll
    for (int mt = 0; mt < 2; ++mt)
#pragma unroll
        for (int nt = 0; nt < NTb; ++nt) {
            int oc = (nt0 + nt) * 16 + col;
            float bs = (oc < OC) ? bias[oc] : 0.f;
#pragma unroll
            for (int j = 0; j < 4; ++j) {
                int p = (mt0 + mt) * 16 + q * 4 + j;
                int gi = ti0 + (p >> 5), gj = tj0 + (p & 31);
                float val = acc[mt][nt][j] + bs;
                if (OMODE == 0) {
                    val = leakyf(val);
                    *((short*)outp + (size_t)(b * HW + gi * W + gj) * 64 + oc) =
                        f2bf(val);
                } else if (OMODE == 1) {
                    if (oc < 72)
                        *((short*)outp + (size_t)(b * HW + gi * W + gj) * 72 + oc) =
                            f2bf(val);
                } else {
                    val = leakyf(val);
                    *((float*)outp + (size_t)(b * 64 + oc) * HW + gi * W + gj) = val;
                }
            }
        }
}

// ---- per-displacement dot map S[b][d][y][x] from channel-last features -----
__global__ void k_corr_t(const float* __restrict__ nrT, float* __restrict__ S) {
    int idx = blockIdx.x * 256 + threadIdx.x;
    if (idx >= BATCH * 49 * 98 * 98) return;
    int x = idx % 98;
    int y = (idx / 98) % 98;
    int d = (idx / (98 * 98)) % 49;
    int b = idx / (98 * 98 * 49);
    int f1i = y - 1, f1j = x - 1;
    int f2i = y + d / 7 - 4, f2j = x + d % 7 - 4;
    float r = 0.f;
    if (f1i >= 0 && f1i < H && f1j >= 0 && f1j < W && f2i >= 0 && f2i < H &&
        f2j >= 0 && f2j < W) {
        const float4* p1 =
            (const float4*)(nrT + ((size_t)b * HW + f1i * W + f1j) * 64);
        const float4* p2 =
            (const float4*)(nrT + ((size_t)b * HW + f2i * W + f2j) * 64);
#pragma unroll
        for (int c = 0; c < 16; ++c) {
            float4 a = p1[c], bb = p2[c];
            r = fmaf(a.x, bb.x, r);
            r = fmaf(a.y, bb.y, r);
            r = fmaf(a.z, bb.z, r);
            r = fmaf(a.w, bb.w, r);
        }
    }
    S[idx] = r;
}

// ---- 3x3 window-sum per displacement + top-3 (stable: strict >) ------------
__global__ void k_topk(const float* __restrict__ S, int* __restrict__ idx3) {
    int p = blockIdx.x * 256 + threadIdx.x;
    if (p >= BATCH * HW) return;
    int b = p / HW, i = (p % HW) / W, j = p % W;
    float v0 = -1e30f, v1 = -1e30f, v2 = -1e30f;
    int d0 = 0, d1 = 0, d2 = 0;
    for (int d = 0; d < 49; ++d) {
        const float* s = S + ((b * 49 + d) * 98 + i) * 98 + j;
        float v = 0.f;
#pragma unroll
        for (int u = 0; u < 3; ++u)
#pragma unroll
            for (int vv = 0; vv < 3; ++vv) v += s[u * 98 + vv];
        if (v > v0) {
            v2 = v1; d2 = d1; v1 = v0; d1 = d0; v0 = v; d0 = d;
        } else if (v > v1) {
            v2 = v1; d2 = d1; v1 = v; d1 = d;
        } else if (v > v2) {
            v2 = v; d2 = d;
        }
    }
    idx3[p * 3 + 0] = d0;
    idx3[p * 3 + 1] = d1;
    idx3[p * 3 + 2] = d2;
}

// ---- pack wnn raw taps into MFMA-B fragments -------------------------------
// B2[nt(4)][n(3)][h2(2)][tap(9)][lane(64)][e(8)]; oc=nt*16+(l&15),
// c=h2*32+(l>>4)*8+e, weight = wnn[oc, n*64+c, u, v], tap=(u*3+v)
__global__ void k_bswz2(const float* __restrict__ wnn, short* __restrict__ B2) {
    int i = blockIdx.x * 256 + threadIdx.x;
    if (i >= 4 * 3 * 2 * 9 * 512) return;
    int e = i & 7, l = (i >> 3) & 63;
    int t = (i >> 9) % 9;
    int h2 = (i / (512 * 9)) % 2;
    int n = (i / (512 * 9 * 2)) % 3;
    int nt = i / (512 * 9 * 2 * 3);
    int oc = nt * 16 + (l & 15);
    int c = h2 * 32 + (l >> 4) * 8 + e;
    int u = t / 3, v = t % 3;
    B2[i] = f2bf(wnn[((oc * 192 + n * 64 + c) * 3 + u) * 3 + v]);
}

// ---- MFMA gather-conv + mask reduce (raw-tap B, acc[yx] selection) ---------
__global__ __launch_bounds__(512) void k_agg_mfma(
    const short* __restrict__ refT, const int* __restrict__ idx3,
    const short* __restrict__ B2, const float* __restrict__ bnn,
    const short* __restrict__ maskT, short* __restrict__ agg) {
    constexpr int PX = 32;
    __shared__ short A_lds[2 * 54 * 64 * 8];  // 110,592 B
    __shared__ int sd[PX][NBR];
    const int p0 = blockIdx.x * PX;
    const int b = p0 / HW;
    const int i0 = (p0 % HW) / W;
    const int j0 = p0 % W;
    const int tid = threadIdx.x;
    if (tid < PX * NBR)
        sd[tid / NBR][tid % NBR] = idx3[(p0 + tid / NBR) * NBR + tid % NBR];
    __syncthreads();
    for (int u = tid; u < PX * NBR * 9 * 8; u += 512) {
        int oct = u & 7;
        int q = u >> 3;
        int rs = q % 9;
        int w2 = q / 9;
        int n = w2 % 3;
        int px = w2 / 3;
        int d = sd[px][n];
        int gi = i0 + d / 7 + rs / 3 - 4;
        int gj = j0 + px + d % 7 + rs % 3 - 4;
        bf16x8 val = {};
        if (gi >= 0 && gi < H && gj >= 0 && gj < W)
            val = *(const bf16x8*)(refT + ((size_t)(b * HW + gi * W + gj)) * 64 +
                                   oct * 8);
        int kb = (n * 9 + rs) * 64 + oct * 8;
        int chunk = (((px >> 4) * 54 + (kb >> 5)) << 6) + (((kb >> 3) & 3) << 4) +
                    (px & 15);
        int byte = chunk << 4;
        byte ^= ((byte >> 8) & 7) << 4;
        *(bf16x8*)((char*)A_lds + byte) = val;
    }
    __syncthreads();
    const int wave = tid >> 6;
    const int lane = tid & 63;
    const int w = wave & 3;      // oc slice
    const int half = wave >> 2;  // pixel group
    f32x4 acc[9] = {};
    const short* Bw = B2 + (size_t)w * (3 * 2 * 9 * 512) + lane * 8;
    const int abase = ((half * 54) * 64 + lane) << 4;
    for (int n = 0; n < 3; ++n) {
#pragma unroll
        for (int h2 = 0; h2 < 2; ++h2) {
            const short* bb = Bw + (n * 2 + h2) * 9 * 512;
            bf16x8 bv[9];
#pragma unroll
            for (int t = 0; t < 9; ++t) bv[t] = *(const bf16x8*)(bb + t * 512);
#pragma unroll
            for (int rs = 0; rs < 9; ++rs) {
                const int kk = (n * 9 + rs) * 2 + h2;
                int ab = abase + (kk << 10);
                ab ^= ((ab >> 8) & 7) << 4;
                bf16x8 a = *(const bf16x8*)((char*)A_lds + ab);
#pragma unroll
                for (int t = 0; t < 9; ++t) {
                    const int y = rs / 3 - t / 3 + 1;
                    const int x = rs % 3 - t % 3 + 1;
                    if (y >= 0 && y < 3 && x >= 0 && x < 3)
                        acc[y * 3 + x] = __builtin_amdgcn_mfma_f32_16x16x32_bf16(
                            a, bv[t], acc[y * 3 + x], 0, 0, 0);
                }
            }
        }
    }
    const int oc = w * 16 + (lane & 15);
    const float bn = bnn[oc];
    const int mrow = (lane >> 4) * 4;
#pragma unroll
    for (int j = 0; j < 4; ++j) {
        int px = half * 16 + mrow + j;
        int ij = i0 * W + j0 + px;
        const short* mb = maskT + (size_t)(b * HW + ij) * 72 + (oc >> 3) * 9;
        float sacc = 0.f;
#pragma unroll
        for (int yx = 0; yx < 9; ++yx) {
            float gv = leakyf(acc[yx][j] + bn);
            sacc += gv * bf2f(mb[yx]);
        }
        agg[(size_t)(b * HW + ij) * 64 + oc] = f2bf(leakyf(sacc));
    }
}

extern "C" void kernel_launch(void* const* d_in, const int* in_sizes, int n_in,
                              void* d_out, int out_size, void* d_ws,
                              size_t ws_size, hipStream_t stream) {
    const float* ref = (const float*)d_in[0];
    const float* w1 = (const float*)d_in[1];
    const float* b1 = (const float*)d_in[2];
    const float* w2 = (const float*)d_in[3];
    const float* b2 = (const float*)d_in[4];
    const float* w3 = (const float*)d_in[5];
    const float* b3 = (const float*)d_in[6];
    const float* w4 = (const float*)d_in[7];
    const float* b4 = (const float*)d_in[8];
    const float* wm = (const float*)d_in[9];
    const float* bm = (const float*)d_in[10];
    const float* wnn = (const float*)d_in[11];
    const float* bnn = (const float*)d_in[12];
    const float* wf = (const float*)d_in[13];
    const float* bf = (const float*)d_in[14];

    char* ws = (char*)d_ws;
    constexpr size_t O_NRT = 0;
    constexpr size_t O_S = O_NRT + (size_t)BATCH * HW * 64 * 4;
    constexpr size_t O_REFT = O_S + (size_t)BATCH * 49 * 98 * 98 * 4;
    constexpr size_t O_X1 = O_REFT + (size_t)BATCH * HW * 64 * 2;
    constexpr size_t O_X2 = O_X1 + (size_t)BATCH * HW * 64 * 2;
    constexpr size_t O_MASKT = O_X2 + (size_t)BATCH * HW * 64 * 2;
    constexpr size_t O_IDX = O_MASKT + (size_t)BATCH * HW * 72 * 2;
    constexpr size_t O_P1 = O_IDX + (size_t)BATCH * HW * 3 * 4;
    constexpr size_t O_P2 = O_P1 + 73728 * 2;
    constexpr size_t O_P3 = O_P2 + 73728 * 2;
    constexpr size_t O_P4 = O_P3 + 28672 * 2;
    constexpr size_t O_PM = O_P4 + 28672 * 2;
    constexpr size_t O_PF = O_PM + 46080 * 2;

    float* NRT = (float*)(ws + O_NRT);
    float* S = (float*)(ws + O_S);
    short* BSWZ2 = (short*)(ws + O_S);  // aliased: written after topk
    short* REFT = (short*)(ws + O_REFT);
    short* X1 = (short*)(ws + O_X1);
    short* X2 = (short*)(ws + O_X2);
    short* MASKT = (short*)(ws + O_MASKT);
    int* IDX = (int*)(ws + O_IDX);
    short* P1 = (short*)(ws + O_P1);
    short* P2 = (short*)(ws + O_P2);
    short* P3 = (short*)(ws + O_P3);
    short* P4 = (short*)(ws + O_P4);
    short* PM = (short*)(ws + O_PM);
    short* PF = (short*)(ws + O_PF);

    // input prep + weight packing
    k_pre<<<(BATCH * HW + 255) / 256, 256, 0, stream>>>(ref, REFT, NRT);
    k_prep<<<144, 256, 0, stream>>>(w1, P1, 64, 64, 128, 3, 3, 4, 1, 36864);
    k_prep<<<144, 256, 0, stream>>>(w2, P2, 64, 64, 64, 3, 3, 4, 0, 36864);
    k_prep<<<112, 256, 0, stream>>>(w3, P3, 64, 64, 64, 7, 1, 4, 0, 28672);
    k_prep<<<112, 256, 0, stream>>>(w4, P4, 64, 64, 64, 1, 7, 4, 0, 28672);
    k_prep<<<180, 256, 0, stream>>>(wm, PM, 72, 64, 64, 3, 3, 5, 0, 46080);
    k_prep<<<288, 256, 0, stream>>>(wf, PF, 64, 128, 128, 3, 3, 4, 0, 73728);

    dim3 cgrid2(3, 12, BATCH * 2);
    dim3 cgrid1(3, 12, BATCH);
    // mask branch (MFMA convs, bf16 channel-last chain, OC split x2)
    k_cmfma<3, 3, 64, 64, 0, true, 2><<<cgrid2, 512, 0, stream>>>(REFT, nullptr, P1, b1, X1);
    k_cmfma<3, 3, 64, 64, 0, true, 2><<<cgrid2, 512, 0, stream>>>(X1, nullptr, P2, b2, X2);
    k_cmfma<7, 1, 64, 64, 0, true, 2><<<cgrid2, 512, 0, stream>>>(X2, nullptr, P3, b3, X1);
    k_cmfma<1, 7, 64, 64, 0, true, 2><<<cgrid2, 512, 0, stream>>>(X1, nullptr, P4, b4, X2);
    k_cmfma<3, 3, 64, 72, 1, true, 1><<<cgrid1, 512, 0, stream>>>(X2, nullptr, PM, bm, MASKT);

    // correlation branch
    k_corr_t<<<(BATCH * 49 * 98 * 98 + 255) / 256, 256, 0, stream>>>(NRT, S);
    k_topk<<<BATCH * HW / 256, 256, 0, stream>>>(S, IDX);

    // raw-tap W2 pack (into dead S region)
    k_bswz2<<<432, 256, 0, stream>>>(wnn, BSWZ2);

    // MFMA gather-conv + mask-weighted aggregate -> X1 (bf16 ch-last)
    k_agg_mfma<<<BATCH * HW / 32, 512, 0, stream>>>(REFT, IDX, BSWZ2, bnn, MASKT, X1);

    // final fusion conv: concat([ref, agg]) -> NCHW fp32 out
    k_cmfma<3, 3, 128, 64, 2, false, 1><<<cgrid1, 512, 0, stream>>>(REFT, X1, PF, bf, d_out);
}